// Round 1
// baseline (8052.444 us; speedup 1.0000x reference)
//
#include <hip/hip_runtime.h>
#include <math.h>

#define B_   4
#define M_   80
#define TMEL 63
#define R_   120
#define S_   240
#define Q_   256
#define NB_  16
#define L_   15872
#define TT   32
#define TH   16

// ---------------------------------------------------------------------------
// Upsample: cond[b,c,t] = b_up[c] + sum_{i,m} w_up[m,c,400+t-256i]*mel[b,m,i]
// valid taps: 0 <= q=400+t-256i <= 799, 0 <= i <= 62
// ---------------------------------------------------------------------------
__global__ __launch_bounds__(256) void upsample_kernel(
    const float* __restrict__ mel, const float* __restrict__ w_up,
    const float* __restrict__ b_up, float* __restrict__ cond)
{
  const int idx = blockIdx.x * 256 + threadIdx.x;   // over B*M_*L_ exactly
  const int t = idx % L_;
  const int c = (idx / L_) % M_;
  const int b = idx / (L_ * M_);
  int i_lo = (t >= 400) ? (((t - 400) >> 8) + 1) : 0;   // ceil((t-399)/256) clamped
  int i_hi = (t + 400) >> 8;
  if (i_hi > TMEL - 1) i_hi = TMEL - 1;
  float acc = b_up[c];
  for (int i = i_lo; i <= i_hi; ++i) {
    const int q = 400 + t - (i << 8);
    const float* __restrict__ wp = w_up + c * 800 + q;       // + m*64000
    const float* __restrict__ mp = mel + b * (M_ * TMEL) + i; // + m*63
#pragma unroll 8
    for (int m = 0; m < M_; ++m)
      acc += wp[m * (M_ * 800)] * mp[m * TMEL];
  }
  cond[idx] = acc;
}

// ---------------------------------------------------------------------------
// Input conv: res[b,r,t] = w_in[r]*wav[b,t] + b_in[r]
// ---------------------------------------------------------------------------
__global__ __launch_bounds__(256) void in_conv_kernel(
    const float* __restrict__ wav, const float* __restrict__ w_in,
    const float* __restrict__ b_in, float* __restrict__ res)
{
  const int idx = blockIdx.x * 256 + threadIdx.x;   // over B*R_*L_ exactly
  const int t = idx % L_;
  const int r = (idx / L_) % R_;
  const int b = idx / (L_ * R_);
  res[idx] = w_in[r] * wav[b * L_ + t] + b_in[r];
}

// ---------------------------------------------------------------------------
// One residual block. Tile: 32 timesteps x all channels, one batch per WG.
// LDS: sA=res[t-d] (aliased to z later), sB=res[t], sC=cond, sG=gated.
// ---------------------------------------------------------------------------
__global__ __launch_bounds__(256) void block_kernel(
    const float* __restrict__ res_in, float* __restrict__ res_out,
    float* __restrict__ skips, const float* __restrict__ cond,
    const float* __restrict__ wg, const float* __restrict__ bg,
    const float* __restrict__ wc, const float* __restrict__ bc,
    const float* __restrict__ wr, const float* __restrict__ br,
    const float* __restrict__ wsk, const float* __restrict__ bs,
    const int d, const int first)
{
  __shared__ __align__(16) float sA[R_][TT];       // res[t-d]; later z
  __shared__ __align__(16) float sB[R_][TT];       // res[t]
  __shared__ __align__(16) float sC[M_][TT];       // cond tile
  __shared__ __align__(16) float sG[2 * R_][TT];   // gated

  const int tid = threadIdx.x;
  const int b = blockIdx.y;
  const int t0 = blockIdx.x * TT;

  const float* __restrict__ resb = res_in + (size_t)b * R_ * L_;
  for (int idx = tid; idx < R_ * TT; idx += 256) {
    const int r = idx >> 5, tt = idx & 31;
    const int ta = t0 + tt - d;
    sA[r][tt] = (ta >= 0) ? resb[r * L_ + ta] : 0.0f;
    sB[r][tt] = resb[r * L_ + t0 + tt];
  }
  const float* __restrict__ condb = cond + (size_t)b * M_ * L_ + t0;
  for (int idx = tid; idx < M_ * TT; idx += 256) {
    const int m = idx >> 5, tt = idx & 31;
    sC[m][tt] = condb[m * L_ + tt];
  }
  __syncthreads();

  const int tx = tid & 7;        // 8 groups of 4 timesteps
  const int ty = tid >> 3;       // 0..31 -> channel pairs
  const int ttb = tx * 4;

  // ---- Phase 2: gated[c][tt] for c in 0..239 ----
  for (int cc = 0; cc < 4; ++cc) {
    const int p = ty + 32 * cc;            // channel pair, wave-uniform-ish
    if (p < 120) {
      const int c0 = 2 * p, c1 = c0 + 1;
      const float bias0 = bg[c0] + bc[c0];
      const float bias1 = bg[c1] + bc[c1];
      float a0x = bias0, a0y = bias0, a0z = bias0, a0w = bias0;
      float a1x = bias1, a1y = bias1, a1z = bias1, a1w = bias1;
      const float2* __restrict__ wgp0 = (const float2*)(wg + c0 * (R_ * 2));
      const float2* __restrict__ wgp1 = (const float2*)(wg + c1 * (R_ * 2));
#pragma unroll 4
      for (int r = 0; r < R_; ++r) {
        const float2 w0 = wgp0[r];
        const float2 w1 = wgp1[r];
        const float4 av = *(const float4*)&sA[r][ttb];
        const float4 bv = *(const float4*)&sB[r][ttb];
        a0x += w0.x * av.x + w0.y * bv.x;
        a0y += w0.x * av.y + w0.y * bv.y;
        a0z += w0.x * av.z + w0.y * bv.z;
        a0w += w0.x * av.w + w0.y * bv.w;
        a1x += w1.x * av.x + w1.y * bv.x;
        a1y += w1.x * av.y + w1.y * bv.y;
        a1z += w1.x * av.z + w1.y * bv.z;
        a1w += w1.x * av.w + w1.y * bv.w;
      }
      const float* __restrict__ wcp0 = wc + c0 * M_;
      const float* __restrict__ wcp1 = wc + c1 * M_;
#pragma unroll 4
      for (int m = 0; m < M_; ++m) {
        const float u0 = wcp0[m], u1 = wcp1[m];
        const float4 cv = *(const float4*)&sC[m][ttb];
        a0x += u0 * cv.x; a0y += u0 * cv.y; a0z += u0 * cv.z; a0w += u0 * cv.w;
        a1x += u1 * cv.x; a1y += u1 * cv.y; a1z += u1 * cv.z; a1w += u1 * cv.w;
      }
      *(float4*)&sG[c0][ttb] = make_float4(a0x, a0y, a0z, a0w);
      *(float4*)&sG[c1][ttb] = make_float4(a1x, a1y, a1z, a1w);
    }
  }
  __syncthreads();

  // ---- Phase 3: z = tanh(f)*sigmoid(g), written into sA ----
  for (int idx = tid; idx < R_ * TT; idx += 256) {
    const int r = idx >> 5, tt = idx & 31;
    const float f = sG[r][tt];
    const float g = sG[r + R_][tt];
    sA[r][tt] = tanhf(f) * (1.0f / (1.0f + __expf(-g)));
  }
  __syncthreads();

  // ---- Phase 4a: skips += w_skip @ z + b_skip ----
  for (int cc = 0; cc < 4; ++cc) {
    const int p = ty + 32 * cc;
    if (p < 120) {
      const int s0 = 2 * p, s1 = s0 + 1;
      float a0x = bs[s0], a0y = bs[s0], a0z = bs[s0], a0w = bs[s0];
      float a1x = bs[s1], a1y = bs[s1], a1z = bs[s1], a1w = bs[s1];
      const float* __restrict__ w0p = wsk + s0 * R_;
      const float* __restrict__ w1p = wsk + s1 * R_;
#pragma unroll 4
      for (int r = 0; r < R_; ++r) {
        const float w0 = w0p[r], w1 = w1p[r];
        const float4 zv = *(const float4*)&sA[r][ttb];
        a0x += w0 * zv.x; a0y += w0 * zv.y; a0z += w0 * zv.z; a0w += w0 * zv.w;
        a1x += w1 * zv.x; a1y += w1 * zv.y; a1z += w1 * zv.z; a1w += w1 * zv.w;
      }
      float* p0 = skips + ((size_t)b * S_ + s0) * L_ + t0 + ttb;
      float* p1 = skips + ((size_t)b * S_ + s1) * L_ + t0 + ttb;
      if (!first) {
        const float4 o0 = *(const float4*)p0;
        const float4 o1 = *(const float4*)p1;
        a0x += o0.x; a0y += o0.y; a0z += o0.z; a0w += o0.w;
        a1x += o1.x; a1y += o1.y; a1z += o1.z; a1w += o1.w;
      }
      *(float4*)p0 = make_float4(a0x, a0y, a0z, a0w);
      *(float4*)p1 = make_float4(a1x, a1y, a1z, a1w);
    }
  }

  // ---- Phase 4b: res_out = res_in + w_res @ z + b_res ----
  for (int cc = 0; cc < 2; ++cc) {
    const int p = ty + 32 * cc;
    if (p < 60) {
      const int r0 = 2 * p, r1 = r0 + 1;
      const float4 base0 = *(const float4*)&sB[r0][ttb];
      const float4 base1 = *(const float4*)&sB[r1][ttb];
      float a0x = base0.x + br[r0], a0y = base0.y + br[r0];
      float a0z = base0.z + br[r0], a0w = base0.w + br[r0];
      float a1x = base1.x + br[r1], a1y = base1.y + br[r1];
      float a1z = base1.z + br[r1], a1w = base1.w + br[r1];
      const float* __restrict__ w0p = wr + r0 * R_;
      const float* __restrict__ w1p = wr + r1 * R_;
#pragma unroll 4
      for (int r = 0; r < R_; ++r) {
        const float w0 = w0p[r], w1 = w1p[r];
        const float4 zv = *(const float4*)&sA[r][ttb];
        a0x += w0 * zv.x; a0y += w0 * zv.y; a0z += w0 * zv.z; a0w += w0 * zv.w;
        a1x += w1 * zv.x; a1y += w1 * zv.y; a1z += w1 * zv.z; a1w += w1 * zv.w;
      }
      float* p0 = res_out + ((size_t)b * R_ + r0) * L_ + t0 + ttb;
      float* p1 = res_out + ((size_t)b * R_ + r1) * L_ + t0 + ttb;
      *(float4*)p0 = make_float4(a0x, a0y, a0z, a0w);
      *(float4*)p1 = make_float4(a1x, a1y, a1z, a1w);
    }
  }
}

// ---------------------------------------------------------------------------
// Head: h = relu(W_h1 @ relu(skips) + b_h1); logits = W_h2 @ h + b_h2
// ---------------------------------------------------------------------------
__global__ __launch_bounds__(256) void head_kernel(
    const float* __restrict__ skips,
    const float* __restrict__ wh1, const float* __restrict__ bh1,
    const float* __restrict__ wh2, const float* __restrict__ bh2,
    float* __restrict__ out)
{
  __shared__ __align__(16) float sS[S_][TH];
  __shared__ __align__(16) float sH[Q_][TH];
  const int tid = threadIdx.x;
  const int b = blockIdx.y;
  const int t0 = blockIdx.x * TH;

  for (int idx = tid; idx < S_ * TH; idx += 256) {
    const int s = idx >> 4, tt = idx & 15;
    const float v = skips[((size_t)b * S_ + s) * L_ + t0 + tt];
    sS[s][tt] = v > 0.0f ? v : 0.0f;
  }
  __syncthreads();

  const int tx = tid & 3, ty = tid >> 2;   // 4 tt-groups x 64 channel-pairs
  const int ttb = tx * 4;

  for (int cc = 0; cc < 2; ++cc) {
    const int p = ty + 64 * cc;            // 0..127
    const int q0 = 2 * p, q1 = q0 + 1;
    float a0x = bh1[q0], a0y = bh1[q0], a0z = bh1[q0], a0w = bh1[q0];
    float a1x = bh1[q1], a1y = bh1[q1], a1z = bh1[q1], a1w = bh1[q1];
    const float* __restrict__ w0p = wh1 + q0 * S_;
    const float* __restrict__ w1p = wh1 + q1 * S_;
#pragma unroll 4
    for (int s = 0; s < S_; ++s) {
      const float w0 = w0p[s], w1 = w1p[s];
      const float4 sv = *(const float4*)&sS[s][ttb];
      a0x += w0 * sv.x; a0y += w0 * sv.y; a0z += w0 * sv.z; a0w += w0 * sv.w;
      a1x += w1 * sv.x; a1y += w1 * sv.y; a1z += w1 * sv.z; a1w += w1 * sv.w;
    }
    *(float4*)&sH[q0][ttb] = make_float4(fmaxf(a0x, 0.f), fmaxf(a0y, 0.f),
                                         fmaxf(a0z, 0.f), fmaxf(a0w, 0.f));
    *(float4*)&sH[q1][ttb] = make_float4(fmaxf(a1x, 0.f), fmaxf(a1y, 0.f),
                                         fmaxf(a1z, 0.f), fmaxf(a1w, 0.f));
  }
  __syncthreads();

  for (int cc = 0; cc < 2; ++cc) {
    const int p = ty + 64 * cc;
    const int q0 = 2 * p, q1 = q0 + 1;
    float a0x = bh2[q0], a0y = bh2[q0], a0z = bh2[q0], a0w = bh2[q0];
    float a1x = bh2[q1], a1y = bh2[q1], a1z = bh2[q1], a1w = bh2[q1];
    const float* __restrict__ w0p = wh2 + q0 * Q_;
    const float* __restrict__ w1p = wh2 + q1 * Q_;
#pragma unroll 4
    for (int q = 0; q < Q_; ++q) {
      const float w0 = w0p[q], w1 = w1p[q];
      const float4 hv = *(const float4*)&sH[q][ttb];
      a0x += w0 * hv.x; a0y += w0 * hv.y; a0z += w0 * hv.z; a0w += w0 * hv.w;
      a1x += w1 * hv.x; a1y += w1 * hv.y; a1z += w1 * hv.z; a1w += w1 * hv.w;
    }
    float* p0 = out + ((size_t)b * Q_ + q0) * L_ + t0 + ttb;
    float* p1 = out + ((size_t)b * Q_ + q1) * L_ + t0 + ttb;
    *(float4*)p0 = make_float4(a0x, a0y, a0z, a0w);
    *(float4*)p1 = make_float4(a1x, a1y, a1z, a1w);
  }
}

// ---------------------------------------------------------------------------
extern "C" void kernel_launch(void* const* d_in, const int* in_sizes, int n_in,
                              void* d_out, int out_size, void* d_ws, size_t ws_size,
                              hipStream_t stream) {
  const float* wav    = (const float*)d_in[0];
  const float* mel    = (const float*)d_in[1];
  const float* w_up   = (const float*)d_in[2];
  const float* b_up   = (const float*)d_in[3];
  const float* w_in   = (const float*)d_in[4];
  const float* b_in   = (const float*)d_in[5];
  const float* w_gate = (const float*)d_in[6];
  const float* b_gate = (const float*)d_in[7];
  const float* w_cond = (const float*)d_in[8];
  const float* b_cond = (const float*)d_in[9];
  const float* w_res  = (const float*)d_in[10];
  const float* b_res  = (const float*)d_in[11];
  const float* w_skip = (const float*)d_in[12];
  const float* b_skip = (const float*)d_in[13];
  const float* w_h1   = (const float*)d_in[14];
  const float* b_h1   = (const float*)d_in[15];
  const float* w_h2   = (const float*)d_in[16];
  const float* b_h2   = (const float*)d_in[17];
  float* out = (float*)d_out;

  float* cond  = (float*)d_ws;                       // B*M*L   = 5,079,040 f
  float* res0  = cond  + (size_t)B_ * M_ * L_;       // B*R*L   = 7,618,560 f
  float* res1  = res0  + (size_t)B_ * R_ * L_;       // B*R*L
  float* skips = res1  + (size_t)B_ * R_ * L_;       // B*S*L   = 15,237,120 f
  // total 142.2 MB of d_ws

  upsample_kernel<<<(B_ * M_ * L_) / 256, 256, 0, stream>>>(mel, w_up, b_up, cond);
  in_conv_kernel<<<(B_ * R_ * L_) / 256, 256, 0, stream>>>(wav, w_in, b_in, res0);

  dim3 bgrid(L_ / TT, B_);
  for (int i = 0; i < NB_; ++i) {
    const int d = 1 << (i & 7);
    const float* rin  = (i & 1) ? res1 : res0;
    float*       rout = (i & 1) ? res0 : res1;
    block_kernel<<<bgrid, 256, 0, stream>>>(
        rin, rout, skips, cond,
        w_gate + (size_t)i * 2 * R_ * R_ * 2, b_gate + i * 2 * R_,
        w_cond + (size_t)i * 2 * R_ * M_,     b_cond + i * 2 * R_,
        w_res  + (size_t)i * R_ * R_,         b_res  + i * R_,
        w_skip + (size_t)i * S_ * R_,         b_skip + i * S_,
        d, (i == 0) ? 1 : 0);
  }

  dim3 hgrid(L_ / TH, B_);
  head_kernel<<<hgrid, 256, 0, stream>>>(skips, w_h1, b_h1, w_h2, b_h2, out);
}

// Round 2
// 3284.876 us; speedup vs baseline: 2.4514x; 2.4514x over previous
//
#include <hip/hip_runtime.h>
#include <math.h>

#define B_   4
#define M_   80
#define TMEL 63
#define R_   120
#define S_   240
#define Q_   256
#define NB_  16
#define L_   15872

typedef float  f32x4  __attribute__((ext_vector_type(4)));
typedef short  bf16x8 __attribute__((ext_vector_type(8)));
typedef short  short4_t __attribute__((ext_vector_type(4)));

__device__ __forceinline__ short f2bf(float x) {
  unsigned u = __builtin_bit_cast(unsigned, x);
  u += 0x7fffu + ((u >> 16) & 1u);
  return (short)(u >> 16);
}
__device__ __forceinline__ float bf2f(unsigned short s) {
  unsigned u = ((unsigned)s) << 16;
  return __builtin_bit_cast(float, u);
}

// ---------------------------------------------------------------------------
// Upsample (unchanged from R1): cond_f32[b][c][t]
// ---------------------------------------------------------------------------
__global__ __launch_bounds__(256) void upsample_kernel(
    const float* __restrict__ mel, const float* __restrict__ w_up,
    const float* __restrict__ b_up, float* __restrict__ cond)
{
  const int idx = blockIdx.x * 256 + threadIdx.x;
  const int t = idx % L_;
  const int c = (idx / L_) % M_;
  const int b = idx / (L_ * M_);
  int i_lo = (t >= 400) ? (((t - 400) >> 8) + 1) : 0;
  int i_hi = (t + 400) >> 8;
  if (i_hi > TMEL - 1) i_hi = TMEL - 1;
  float acc = b_up[c];
  for (int i = i_lo; i <= i_hi; ++i) {
    const int q = 400 + t - (i << 8);
    const float* __restrict__ wp = w_up + c * 800 + q;
    const float* __restrict__ mp = mel + b * (M_ * TMEL) + i;
#pragma unroll 8
    for (int m = 0; m < M_; ++m)
      acc += wp[m * (M_ * 800)] * mp[m * TMEL];
  }
  cond[idx] = acc;
}

// cond_f32 [b][c][t] -> cond_bf16 [b][t][80]
__global__ __launch_bounds__(256) void transpose_cond_kernel(
    const float* __restrict__ cf, short* __restrict__ cb)
{
  __shared__ float T[M_][65];
  const int b = blockIdx.y;
  const int t0 = blockIdx.x * 64;
  for (int idx = threadIdx.x; idx < M_ * 64; idx += 256) {
    const int t = idx & 63, c = idx >> 6;
    T[c][t] = cf[((size_t)(b * M_ + c)) * L_ + t0 + t];
  }
  __syncthreads();
  for (int idx = threadIdx.x; idx < 64 * M_; idx += 256) {
    const int c = idx % M_, t = idx / M_;
    cb[((size_t)b * L_ + t0 + t) * M_ + c] = f2bf(T[c][t]);
  }
}

// res0[b][t][128] fp32: r<120 -> w_in[r]*wav+b_in[r], else 0
__global__ __launch_bounds__(256) void in_conv_kernel(
    const float* __restrict__ wav, const float* __restrict__ w_in,
    const float* __restrict__ b_in, float* __restrict__ res)
{
  const int idx = blockIdx.x * 256 + threadIdx.x;   // B*L*128
  const int r = idx & 127;
  const int rem = idx >> 7;
  const int t = rem % L_;
  const int b = rem / L_;
  res[idx] = (r < R_) ? (w_in[r] * wav[b * L_ + t] + b_in[r]) : 0.0f;
}

// ---------------------------------------------------------------------------
// Weight prepacks (bf16, k-contiguous rows)
// ---------------------------------------------------------------------------
// W1p[i][c'][320], c'=2r->orig r (f), c'=2r+1->orig 120+r (g)
__global__ __launch_bounds__(256) void prepack_w1_kernel(
    const float* __restrict__ wg, const float* __restrict__ wc,
    short* __restrict__ W1p)
{
  const int idx = blockIdx.x * 256 + threadIdx.x;   // 16*240*320
  const int k = idx % 320;
  const int cp = (idx / 320) % 240;
  const int i = idx / (320 * 240);
  const int r = cp >> 1;
  const int corig = (cp & 1) ? (120 + r) : r;
  float val;
  if (k < 120)      val = wg[((size_t)(i * 240 + corig) * 120 + k) * 2 + 0];
  else if (k < 240) val = wg[((size_t)(i * 240 + corig) * 120 + (k - 120)) * 2 + 1];
  else              val = wc[(size_t)(i * 240 + corig) * 80 + (k - 240)];
  W1p[idx] = f2bf(val);
}

// W2p[i][s'][128]: s'<240 -> w_skip row, 240<=s'<360 -> w_res row, else 0
__global__ __launch_bounds__(256) void prepack_w2_kernel(
    const float* __restrict__ wsk, const float* __restrict__ wr,
    short* __restrict__ W2p)
{
  const int idx = blockIdx.x * 256 + threadIdx.x;   // 16*368*128
  const int k = idx % 128;
  const int sp = (idx / 128) % 368;
  const int i = idx / (128 * 368);
  float val = 0.0f;
  if (k < 120) {
    if (sp < 240)      val = wsk[(size_t)(i * 240 + sp) * 120 + k];
    else if (sp < 360) val = wr[(size_t)(i * 120 + (sp - 240)) * 120 + k];
  }
  W2p[idx] = f2bf(val);
}

__global__ __launch_bounds__(256) void prepack_rest_kernel(
    const float* __restrict__ wh1, const float* __restrict__ wh2,
    const float* __restrict__ bg, const float* __restrict__ bc,
    const float* __restrict__ bs, const float* __restrict__ br,
    short* __restrict__ Wh1p, short* __restrict__ Wh2p,
    float* __restrict__ bias1p, float* __restrict__ bias2p)
{
  const int idx = blockIdx.x * 256 + threadIdx.x;   // 140800
  if (idx < 65536) {
    const int q = idx >> 8, k = idx & 255;
    Wh1p[idx] = f2bf(k < 240 ? wh1[q * 240 + k] : 0.0f);
  } else if (idx < 131072) {
    Wh2p[idx - 65536] = f2bf(wh2[idx - 65536]);
  } else if (idx < 134912) {
    const int j = idx - 131072;
    const int i = j / 240, cp = j % 240;
    const int r = cp >> 1;
    const int corig = (cp & 1) ? (120 + r) : r;
    bias1p[j] = bg[i * 240 + corig] + bc[i * 240 + corig];
  } else if (idx < 140800) {
    const int j = idx - 134912;
    const int i = j / 368, sp = j % 368;
    float v = 0.0f;
    if (sp < 240)      v = bs[i * 240 + sp];
    else if (sp < 360) v = br[i * 120 + (sp - 240)];
    bias2p[j] = v;
  }
}

// ---------------------------------------------------------------------------
// MFMA residual block. WG = 256 thr (4 waves), 64 timesteps, one batch row.
// GEMM1: gated[240 x 64] = W1[240 x 320] @ X[320 x 64]  (X = [res(t-d);res(t);cond])
// GEMM2: [skip;res][368 x 64] = W2[368 x 128] @ Z[128 x 64]
// A-operand = activations in LDS [t][k] bf16; B = prepacked weights (global).
// ---------------------------------------------------------------------------
#define KP1 328   // 320 + 8 pad (stride ≡ 4 dwords mod 32 -> uniform banks)
#define KP2 136   // 128 + 8

__global__ __launch_bounds__(256, 2) void block_mfma_kernel(
    const float* __restrict__ res_in, float* __restrict__ res_out,
    unsigned short* __restrict__ skips, const short* __restrict__ condb,
    const short* __restrict__ W1, const short* __restrict__ W2,
    const float* __restrict__ bias1, const float* __restrict__ bias2,
    const int d, const int first)
{
  __shared__ __align__(16) short Xs[64 * KP1];
  __shared__ __align__(16) short Zs[64 * KP2];

  const int tid = threadIdx.x;
  const int bb = blockIdx.y;
  const int t0 = blockIdx.x * 64;

  // ---- stage X: rows t, k: [0,120)=res[t-d], [120,240)=res[t], [240,320)=cond
  for (int idx = tid; idx < 4096; idx += 256) {
    const int c = idx & 63, trw = idx >> 6;
    if (c < 60) {
      const int tap1 = (c >= 30) ? 1 : 0;
      const int cc = tap1 ? (c - 30) : c;
      const int ts = t0 + trw - (tap1 ? 0 : d);
      float4 v = make_float4(0.f, 0.f, 0.f, 0.f);
      if (ts >= 0)
        v = *(const float4*)(res_in + ((size_t)(bb * L_ + ts) * 128 + cc * 4));
      short4_t s;
      s.x = f2bf(v.x); s.y = f2bf(v.y); s.z = f2bf(v.z); s.w = f2bf(v.w);
      *(short4_t*)&Xs[trw * KP1 + tap1 * 120 + cc * 4] = s;
    }
  }
  for (int idx = tid; idx < 1024; idx += 256) {
    const int c = idx & 15, trw = idx >> 4;
    if (c < 10) {
      const int4 v = *(const int4*)(condb + ((size_t)(bb * L_ + t0 + trw) * M_ + c * 8));
      *(int4*)&Xs[trw * KP1 + 240 + c * 8] = v;
    }
  }
  __syncthreads();

  const int lane = tid & 63;
  const int wv = tid >> 6;
  const int col = lane & 15;
  const int quad = lane >> 4;
  const int kq = quad * 8;
  const int trow = wv * 16 + col;

  // ---- GEMM1 ----
  f32x4 acc[15];
#pragma unroll
  for (int i = 0; i < 15; ++i) acc[i] = (f32x4)(0.f);
  {
    const short* Xa = &Xs[trow * KP1 + kq];
#pragma unroll
    for (int ks = 0; ks < 10; ++ks) {
      bf16x8 a = *(const bf16x8*)(Xa + ks * 32);
      const short* wp = W1 + col * 320 + ks * 32 + kq;
#pragma unroll
      for (int ct = 0; ct < 15; ++ct) {
        bf16x8 b = *(const bf16x8*)(wp + ct * 16 * 320);
        acc[ct] = __builtin_amdgcn_mfma_f32_16x16x32_bf16(a, b, acc[ct], 0, 0, 0);
      }
    }
  }

  // ---- gating: even col = f, odd col = g (same r); z -> Zs[t][r] ----
#pragma unroll
  for (int ct = 0; ct < 15; ++ct) {
    const int cp = ct * 16 + col;
    const float bias = bias1[cp];
#pragma unroll
    for (int reg = 0; reg < 4; ++reg) {
      float v = acc[ct][reg] + bias;
      v = fminf(fmaxf(v, -15.f), 15.f);
      const float e = __expf((lane & 1) ? -v : 2.0f * v);
      const float rc = __builtin_amdgcn_rcpf(e + 1.0f);
      const float u = (lane & 1) ? rc : (e - 1.0f) * rc;   // sigmoid(g) | tanh(f)
      const float p = __shfl_xor(u, 1, 64);
      if (!(lane & 1)) {
        const int t = wv * 16 + quad * 4 + reg;
        Zs[t * KP2 + ct * 8 + (col >> 1)] = f2bf(u * p);
      }
    }
  }
  if (lane < 16) {  // zero k-pad cols 120..127 of this wave's rows
    int4 z4 = make_int4(0, 0, 0, 0);
    *(int4*)&Zs[(wv * 16 + lane) * KP2 + 120] = z4;
  }

  // ---- GEMM2 ----
  f32x4 acc2[23];
#pragma unroll
  for (int i = 0; i < 23; ++i) acc2[i] = (f32x4)(0.f);
  {
    const short* Za = &Zs[trow * KP2 + kq];
#pragma unroll
    for (int ks = 0; ks < 4; ++ks) {
      bf16x8 a = *(const bf16x8*)(Za + ks * 32);
      const short* wp = W2 + col * 128 + ks * 32 + kq;
#pragma unroll
      for (int st = 0; st < 23; ++st) {
        bf16x8 b = *(const bf16x8*)(wp + st * 16 * 128);
        acc2[st] = __builtin_amdgcn_mfma_f32_16x16x32_bf16(a, b, acc2[st], 0, 0, 0);
      }
    }
  }

  // ---- epilogue: skips (bf16 RMW) + residual out (fp32) ----
  const int tg0 = t0 + wv * 16 + quad * 4;
#pragma unroll
  for (int st = 0; st < 15; ++st) {
    const int s = st * 16 + col;
    const float b2 = bias2[s];
    unsigned short* sp = skips + ((size_t)(bb * L_ + tg0) * 240 + s);
#pragma unroll
    for (int reg = 0; reg < 4; ++reg) {
      unsigned short* p = sp + (size_t)reg * 240;
      float add = acc2[st][reg] + b2;
      float old = first ? 0.0f : bf2f(*p);
      *p = (unsigned short)f2bf(old + add);
    }
  }
#pragma unroll
  for (int st = 15; st < 23; ++st) {
    const int sp_ = st * 16 + col;
    const int r = sp_ - 240;
    if (r < 120) {
      const float b2 = bias2[sp_];
      const float* rip = res_in + ((size_t)(bb * L_ + tg0) * 128 + r);
      float* rop = res_out + ((size_t)(bb * L_ + tg0) * 128 + r);
#pragma unroll
      for (int reg = 0; reg < 4; ++reg)
        rop[reg * 128] = rip[reg * 128] + acc2[st][reg] + b2;
    }
  }
}

// ---------------------------------------------------------------------------
// Head: logits = Wh2 @ relu(Wh1 @ relu(skips) + bh1) + bh2.  S reused for H.
// ---------------------------------------------------------------------------
#define KPH 264   // 256 + 8

__global__ __launch_bounds__(256, 3) void head_mfma_kernel(
    const unsigned short* __restrict__ skips,
    const short* __restrict__ Wh1, const short* __restrict__ Wh2,
    const float* __restrict__ bh1, const float* __restrict__ bh2,
    float* __restrict__ out)
{
  __shared__ __align__(16) short Ss[64 * KPH];

  const int tid = threadIdx.x;
  const int bb = blockIdx.y;
  const int t0 = blockIdx.x * 64;

  // stage relu(skips) bf16; zero cols 240..255
  for (int idx = tid; idx < 2048; idx += 256) {
    const int c = idx & 31, trw = idx >> 5;
    if (c < 30) {
      int4 v = *(const int4*)(skips + ((size_t)(bb * L_ + t0 + trw) * 240 + c * 8));
      int* vi = (int*)&v;
#pragma unroll
      for (int j = 0; j < 4; ++j) {
        unsigned x = (unsigned)vi[j];
        unsigned lo = x & 0xFFFFu; if (lo & 0x8000u) lo = 0;
        unsigned hi = x >> 16;     if (hi & 0x8000u) hi = 0;
        vi[j] = (int)(lo | (hi << 16));
      }
      *(int4*)&Ss[trw * KPH + c * 8] = v;
    } else {
      *(int4*)&Ss[trw * KPH + c * 8] = make_int4(0, 0, 0, 0);
    }
  }
  __syncthreads();

  const int lane = tid & 63;
  const int wv = tid >> 6;
  const int col = lane & 15;
  const int quad = lane >> 4;
  const int kq = quad * 8;
  const int trow = wv * 16 + col;

  f32x4 acc[16];
#pragma unroll
  for (int i = 0; i < 16; ++i) acc[i] = (f32x4)(0.f);
#pragma unroll
  for (int ks = 0; ks < 8; ++ks) {
    bf16x8 a = *(const bf16x8*)&Ss[trow * KPH + ks * 32 + kq];
    const short* wp = Wh1 + col * 256 + ks * 32 + kq;
#pragma unroll
    for (int ct = 0; ct < 16; ++ct) {
      bf16x8 b = *(const bf16x8*)(wp + ct * 16 * 256);
      acc[ct] = __builtin_amdgcn_mfma_f32_16x16x32_bf16(a, b, acc[ct], 0, 0, 0);
    }
  }
  // h = relu(.) -> same buffer rows (wave-private rows; reads all done)
#pragma unroll
  for (int ct = 0; ct < 16; ++ct) {
    const int q = ct * 16 + col;
    const float b1 = bh1[q];
#pragma unroll
    for (int reg = 0; reg < 4; ++reg) {
      const int t = wv * 16 + quad * 4 + reg;
      Ss[t * KPH + q] = f2bf(fmaxf(acc[ct][reg] + b1, 0.0f));
    }
  }

  f32x4 acc2[16];
#pragma unroll
  for (int i = 0; i < 16; ++i) acc2[i] = (f32x4)(0.f);
#pragma unroll
  for (int ks = 0; ks < 8; ++ks) {
    bf16x8 a = *(const bf16x8*)&Ss[trow * KPH + ks * 32 + kq];
    const short* wp = Wh2 + col * 256 + ks * 32 + kq;
#pragma unroll
    for (int ct = 0; ct < 16; ++ct) {
      bf16x8 b = *(const bf16x8*)(wp + ct * 16 * 256);
      acc2[ct] = __builtin_amdgcn_mfma_f32_16x16x32_bf16(a, b, acc2[ct], 0, 0, 0);
    }
  }
  const int tg0 = t0 + wv * 16 + quad * 4;
#pragma unroll
  for (int ct = 0; ct < 16; ++ct) {
    const int q = ct * 16 + col;
    const float b2 = bh2[q];
    float4 o = make_float4(acc2[ct][0] + b2, acc2[ct][1] + b2,
                           acc2[ct][2] + b2, acc2[ct][3] + b2);
    *(float4*)(out + ((size_t)(bb * Q_ + q)) * L_ + tg0) = o;
  }
}

// ---------------------------------------------------------------------------
extern "C" void kernel_launch(void* const* d_in, const int* in_sizes, int n_in,
                              void* d_out, int out_size, void* d_ws, size_t ws_size,
                              hipStream_t stream) {
  const float* wav    = (const float*)d_in[0];
  const float* mel    = (const float*)d_in[1];
  const float* w_up   = (const float*)d_in[2];
  const float* b_up   = (const float*)d_in[3];
  const float* w_in   = (const float*)d_in[4];
  const float* b_in   = (const float*)d_in[5];
  const float* w_gate = (const float*)d_in[6];
  const float* b_gate = (const float*)d_in[7];
  const float* w_cond = (const float*)d_in[8];
  const float* b_cond = (const float*)d_in[9];
  const float* w_res  = (const float*)d_in[10];
  const float* b_res  = (const float*)d_in[11];
  const float* w_skip = (const float*)d_in[12];
  const float* b_skip = (const float*)d_in[13];
  const float* w_h1   = (const float*)d_in[14];
  const float* b_h1   = (const float*)d_in[15];
  const float* w_h2   = (const float*)d_in[16];
  const float* b_h2   = (const float*)d_in[17];
  float* out = (float*)d_out;

  char* w = (char*)d_ws;
  short* condb   = (short*)w;                       w += (size_t)B_ * L_ * M_ * 2;    // 10,158,080
  float* res0    = (float*)w;                       w += (size_t)B_ * L_ * 128 * 4;   // 32,505,856
  float* res1    = (float*)w;                       w += (size_t)B_ * L_ * 128 * 4;   // 32,505,856
  unsigned short* skips = (unsigned short*)w;       w += (size_t)B_ * L_ * 240 * 2;   // 30,474,240
  short* W1p     = (short*)w;                       w += (size_t)16 * 240 * 320 * 2;  // 2,457,600
  short* W2p     = (short*)w;                       w += (size_t)16 * 368 * 128 * 2;  // 1,507,328
  short* Wh1p    = (short*)w;                       w += (size_t)256 * 256 * 2;
  short* Wh2p    = (short*)w;                       w += (size_t)256 * 256 * 2;
  float* bias1p  = (float*)w;                       w += (size_t)16 * 240 * 4;
  float* bias2p  = (float*)w;                       w += (size_t)16 * 368 * 4;
  float* cond_f32 = res0;   // transient overlay; in_conv overwrites after transpose

  prepack_w1_kernel<<<(16 * 240 * 320) / 256, 256, 0, stream>>>(w_gate, w_cond, W1p);
  prepack_w2_kernel<<<(16 * 368 * 128) / 256, 256, 0, stream>>>(w_skip, w_res, W2p);
  prepack_rest_kernel<<<140800 / 256, 256, 0, stream>>>(
      w_h1, w_h2, b_gate, b_cond, b_skip, b_res, Wh1p, Wh2p, bias1p, bias2p);

  upsample_kernel<<<(B_ * M_ * L_) / 256, 256, 0, stream>>>(mel, w_up, b_up, cond_f32);
  dim3 tgrid(L_ / 64, B_);
  transpose_cond_kernel<<<tgrid, 256, 0, stream>>>(cond_f32, condb);
  in_conv_kernel<<<((size_t)B_ * L_ * 128) / 256, 256, 0, stream>>>(wav, w_in, b_in, res0);

  dim3 bgrid(L_ / 64, B_);
  for (int i = 0; i < NB_; ++i) {
    const int d = 1 << (i & 7);
    const float* rin  = (i & 1) ? res1 : res0;
    float*       rout = (i & 1) ? res0 : res1;
    block_mfma_kernel<<<bgrid, 256, 0, stream>>>(
        rin, rout, skips, condb,
        W1p + (size_t)i * 240 * 320, W2p + (size_t)i * 368 * 128,
        bias1p + i * 240, bias2p + i * 368,
        d, (i == 0) ? 1 : 0);
  }

  head_mfma_kernel<<<bgrid, 256, 0, stream>>>(skips, Wh1p, Wh2p, b_h1, b_h2, out);
}

// Round 3
// 1437.819 us; speedup vs baseline: 5.6005x; 2.2846x over previous
//
#include <hip/hip_runtime.h>
#include <math.h>

#define B_   4
#define M_   80
#define TMEL 63
#define R_   120
#define S_   240
#define Q_   256
#define NB_  16
#define L_   15872

typedef float  f32x4  __attribute__((ext_vector_type(4)));
typedef short  bf16x8 __attribute__((ext_vector_type(8)));
typedef short  short4_t __attribute__((ext_vector_type(4)));

__device__ __forceinline__ short f2bf(float x) {
  unsigned u = __builtin_bit_cast(unsigned, x);
  u += 0x7fffu + ((u >> 16) & 1u);
  return (short)(u >> 16);
}
__device__ __forceinline__ float bf2f(unsigned short s) {
  unsigned u = ((unsigned)s) << 16;
  return __builtin_bit_cast(float, u);
}

// ---------------------------------------------------------------------------
// melT[b][i][m] bf16  <-  mel[b][m][i] f32
// ---------------------------------------------------------------------------
__global__ __launch_bounds__(256) void prep_melT_kernel(
    const float* __restrict__ mel, short* __restrict__ melT)
{
  const int idx = blockIdx.x * 256 + threadIdx.x;
  if (idx >= B_ * TMEL * M_) return;
  const int m = idx % M_;
  const int i = (idx / M_) % TMEL;
  const int b = idx / (M_ * TMEL);
  melT[idx] = f2bf(mel[b * (M_ * TMEL) + m * TMEL + i]);
}

// ---------------------------------------------------------------------------
// Wup[phi][c][j*80+m] bf16: tap j <-> delta = dmin(phi)+j, q = 400+phi+256*delta
// dmin = (phi<112) ? -1 : -2 ;  dmax = (phi<144) ? 1 : 0
// ---------------------------------------------------------------------------
__global__ __launch_bounds__(256) void prep_wup_kernel(
    const float* __restrict__ w_up, short* __restrict__ Wup)
{
  __shared__ float T[M_][65];
  const int c  = blockIdx.x >> 4;
  const int j  = (blockIdx.x >> 2) & 3;
  const int fb = blockIdx.x & 3;
  for (int idx = threadIdx.x; idx < M_ * 64; idx += 256) {
    const int pl = idx & 63, m = idx >> 6;
    const int phi = fb * 64 + pl;
    const int dmin = (phi < 112) ? -1 : -2;
    const int dmax = (phi < 144) ? 1 : 0;
    const int delta = dmin + j;
    float v = 0.0f;
    if (delta <= dmax)
      v = w_up[m * (M_ * 800) + c * 800 + (400 + phi + 256 * delta)];
    T[m][pl] = v;
  }
  __syncthreads();
  for (int idx = threadIdx.x; idx < 64 * M_; idx += 256) {
    const int m = idx % M_, pl = idx / M_;
    const int phi = fb * 64 + pl;
    Wup[((size_t)phi * M_ + c) * 320 + j * 80 + m] = f2bf(T[m][pl]);
  }
}

// ---------------------------------------------------------------------------
// Upsample as per-phase MFMA GEMM: out[(b,n)][c] = sum_k X[(b,n)][k]*Wup[phi][c][k]
// t = phi + 256*n ; X row k=j*80+m = melT[b][n-(dmin+j)][m] (0 if OOB)
// Writes condb[b][t][80] bf16 directly.
// ---------------------------------------------------------------------------
#define KPU 328

__global__ __launch_bounds__(256, 2) void upsample_mfma_kernel(
    const short* __restrict__ melT, const short* __restrict__ Wup,
    const float* __restrict__ b_up, short* __restrict__ condb)
{
  __shared__ __align__(16) short Xu[64 * KPU];
  const int tid = threadIdx.x;
  const int phi = blockIdx.x;
  const int r0 = blockIdx.y * 64;
  const int dmin = (phi < 112) ? -1 : -2;

  for (int idx = tid; idx < 2560; idx += 256) {
    const int v = idx % 10;
    const int j = (idx / 10) & 3;
    const int rl = idx / 40;
    const int rho = r0 + rl;
    const int b = rho / 62;
    const int n = rho - b * 62;
    const int i = n - (dmin + j);
    int4 val = make_int4(0, 0, 0, 0);
    if (b < B_ && i >= 0 && i < TMEL)
      val = *(const int4*)&melT[((size_t)b * TMEL + i) * M_ + v * 8];
    *(int4*)&Xu[rl * KPU + j * 80 + v * 8] = val;
  }
  __syncthreads();

  const int lane = tid & 63;
  const int wv = tid >> 6;
  const int col = lane & 15;
  const int quad = lane >> 4;
  const int kq = quad * 8;

  f32x4 acc[5];
#pragma unroll
  for (int i = 0; i < 5; ++i) acc[i] = (f32x4)(0.f);
#pragma unroll
  for (int ks = 0; ks < 10; ++ks) {
    bf16x8 a = *(const bf16x8*)&Xu[(wv * 16 + col) * KPU + ks * 32 + kq];
#pragma unroll
    for (int ct = 0; ct < 5; ++ct) {
      bf16x8 b = *(const bf16x8*)(Wup + ((size_t)phi * M_ + ct * 16 + col) * 320 + ks * 32 + kq);
      acc[ct] = __builtin_amdgcn_mfma_f32_16x16x32_bf16(a, b, acc[ct], 0, 0, 0);
    }
  }
#pragma unroll
  for (int ct = 0; ct < 5; ++ct) {
    const int c = ct * 16 + col;
    const float bc = b_up[c];
#pragma unroll
    for (int reg = 0; reg < 4; ++reg) {
      const int rho = r0 + wv * 16 + quad * 4 + reg;
      if (rho < 248) {
        const int b = rho / 62;
        const int n = rho - b * 62;
        const int t = phi + (n << 8);
        condb[((size_t)b * L_ + t) * M_ + c] = f2bf(acc[ct][reg] + bc);
      }
    }
  }
}

// res0[b][t][128] fp32: r<120 -> w_in[r]*wav+b_in[r], else 0
__global__ __launch_bounds__(256) void in_conv_kernel(
    const float* __restrict__ wav, const float* __restrict__ w_in,
    const float* __restrict__ b_in, float* __restrict__ res)
{
  const int idx = blockIdx.x * 256 + threadIdx.x;
  const int r = idx & 127;
  const int rem = idx >> 7;
  const int t = rem % L_;
  const int b = rem / L_;
  res[idx] = (r < R_) ? (w_in[r] * wav[b * L_ + t] + b_in[r]) : 0.0f;
}

// ---------------------------------------------------------------------------
// Weight prepacks
// W1p[i][256][320] (rows 240..255 zero), c'=2r->f_r, 2r+1->g_r
// ---------------------------------------------------------------------------
__global__ __launch_bounds__(256) void prepack_w1_kernel(
    const float* __restrict__ wg, const float* __restrict__ wc,
    short* __restrict__ W1p)
{
  const int idx = blockIdx.x * 256 + threadIdx.x;   // 16*256*320
  const int k = idx % 320;
  const int cp = (idx / 320) % 256;
  const int i = idx / (320 * 256);
  float val = 0.0f;
  if (cp < 240) {
    const int r = cp >> 1;
    const int corig = (cp & 1) ? (120 + r) : r;
    if (k < 120)      val = wg[((size_t)(i * 240 + corig) * 120 + k) * 2 + 0];
    else if (k < 240) val = wg[((size_t)(i * 240 + corig) * 120 + (k - 120)) * 2 + 1];
    else              val = wc[(size_t)(i * 240 + corig) * 80 + (k - 240)];
  }
  W1p[idx] = f2bf(val);
}

// W2p[i][384][128]: s'<240 skip rows, 240..359 res rows, else 0
__global__ __launch_bounds__(256) void prepack_w2_kernel(
    const float* __restrict__ wsk, const float* __restrict__ wr,
    short* __restrict__ W2p)
{
  const int idx = blockIdx.x * 256 + threadIdx.x;   // 16*384*128
  const int k = idx % 128;
  const int sp = (idx / 128) % 384;
  const int i = idx / (128 * 384);
  float val = 0.0f;
  if (k < 120) {
    if (sp < 240)      val = wsk[(size_t)(i * 240 + sp) * 120 + k];
    else if (sp < 360) val = wr[(size_t)(i * 120 + (sp - 240)) * 120 + k];
  }
  W2p[idx] = f2bf(val);
}

__global__ __launch_bounds__(256) void prepack_rest_kernel(
    const float* __restrict__ wh1, const float* __restrict__ wh2,
    const float* __restrict__ bg, const float* __restrict__ bc,
    const float* __restrict__ bs, const float* __restrict__ br,
    short* __restrict__ Wh1p, short* __restrict__ Wh2p,
    float* __restrict__ bias1p, float* __restrict__ bias2p)
{
  const int idx = blockIdx.x * 256 + threadIdx.x;   // 141056
  if (idx < 65536) {
    const int q = idx >> 8, k = idx & 255;
    Wh1p[idx] = f2bf(k < 240 ? wh1[q * 240 + k] : 0.0f);
  } else if (idx < 131072) {
    Wh2p[idx - 65536] = f2bf(wh2[idx - 65536]);
  } else if (idx < 134912) {
    const int j = idx - 131072;
    const int i = j / 240, cp = j % 240;
    const int r = cp >> 1;
    const int corig = (cp & 1) ? (120 + r) : r;
    bias1p[j] = bg[i * 240 + corig] + bc[i * 240 + corig];
  } else if (idx < 141056) {
    const int j = idx - 134912;
    const int i = j / 384, sp = j % 384;
    float v = 0.0f;
    if (sp < 240)      v = bs[i * 240 + sp];
    else if (sp < 360) v = br[i * 120 + (sp - 240)];
    bias2p[j] = v;
  }
}

// ---------------------------------------------------------------------------
// MFMA residual block. 4 waves; each wave owns a c-tile strip and ALL 4
// t-tiles (4x B-fragment reuse). Epilogue: skips staged in LDS (Xs reuse),
// cooperative int4 RMW; res written scalar f32 (64B-coalesced).
// ---------------------------------------------------------------------------
#define KP1 328
#define KP2 136
#define SGP 248

__global__ __launch_bounds__(256, 2) void block_mfma_kernel(
    const float* __restrict__ res_in, float* __restrict__ res_out,
    unsigned short* __restrict__ skips, const short* __restrict__ condb,
    const short* __restrict__ W1, const short* __restrict__ W2,
    const float* __restrict__ bias1, const float* __restrict__ bias2,
    const int d, const int first)
{
  __shared__ __align__(16) short Xs[64 * KP1];
  __shared__ __align__(16) short Zs[64 * KP2];

  const int tid = threadIdx.x;
  const int bb = blockIdx.y;
  const int t0 = blockIdx.x * 64;

  // ---- stage X: k [0,120)=res[t-d], [120,240)=res[t], [240,320)=cond
  for (int idx = tid; idx < 4096; idx += 256) {
    const int c = idx & 63, trw = idx >> 6;
    if (c < 60) {
      const int tap1 = (c >= 30) ? 1 : 0;
      const int cc = tap1 ? (c - 30) : c;
      const int ts = t0 + trw - (tap1 ? 0 : d);
      float4 v = make_float4(0.f, 0.f, 0.f, 0.f);
      if (ts >= 0)
        v = *(const float4*)(res_in + ((size_t)(bb * L_ + ts) * 128 + cc * 4));
      short4_t s;
      s.x = f2bf(v.x); s.y = f2bf(v.y); s.z = f2bf(v.z); s.w = f2bf(v.w);
      *(short4_t*)&Xs[trw * KP1 + tap1 * 120 + cc * 4] = s;
    }
  }
  for (int idx = tid; idx < 1024; idx += 256) {
    const int c = idx & 15, trw = idx >> 4;
    if (c < 10) {
      const int4 v = *(const int4*)(condb + ((size_t)(bb * L_ + t0 + trw) * M_ + c * 8));
      *(int4*)&Xs[trw * KP1 + 240 + c * 8] = v;
    }
  }
  __syncthreads();

  const int lane = tid & 63;
  const int wv = tid >> 6;
  const int col = lane & 15;
  const int quad = lane >> 4;
  const int kq = quad * 8;

  // ---- GEMM1: wave wv -> c-tiles [wv*4, wv*4+4), t-tiles 0..3 ----
  f32x4 acc[4][4];   // [tf][ct]
#pragma unroll
  for (int a = 0; a < 4; ++a)
#pragma unroll
    for (int b = 0; b < 4; ++b) acc[a][b] = (f32x4)(0.f);
#pragma unroll
  for (int ks = 0; ks < 10; ++ks) {
    bf16x8 av[4];
#pragma unroll
    for (int tf = 0; tf < 4; ++tf)
      av[tf] = *(const bf16x8*)&Xs[(tf * 16 + col) * KP1 + ks * 32 + kq];
#pragma unroll
    for (int ct = 0; ct < 4; ++ct) {
      bf16x8 b = *(const bf16x8*)(W1 + ((wv * 4 + ct) * 16 + col) * 320 + ks * 32 + kq);
#pragma unroll
      for (int tf = 0; tf < 4; ++tf)
        acc[tf][ct] = __builtin_amdgcn_mfma_f32_16x16x32_bf16(av[tf], b, acc[tf][ct], 0, 0, 0);
    }
  }

  // ---- gating: even col = f, odd col = g; z -> Zs[t][r] ----
#pragma unroll
  for (int ct = 0; ct < 4; ++ct) {
    const int tile = wv * 4 + ct;
    if (tile < 15) {
      const int cp = tile * 16 + col;
      const float bias = bias1[cp];
#pragma unroll
      for (int tf = 0; tf < 4; ++tf) {
#pragma unroll
        for (int reg = 0; reg < 4; ++reg) {
          float v = acc[tf][ct][reg] + bias;
          v = fminf(fmaxf(v, -15.f), 15.f);
          const float e = __expf((lane & 1) ? -v : 2.0f * v);
          const float rc = __builtin_amdgcn_rcpf(e + 1.0f);
          const float u = (lane & 1) ? rc : (e - 1.0f) * rc;
          const float p = __shfl_xor(u, 1, 64);
          if (!(lane & 1)) {
            const int t = tf * 16 + quad * 4 + reg;
            Zs[t * KP2 + tile * 8 + (col >> 1)] = f2bf(u * p);
          }
        }
      }
    }
  }
  if (lane < 16)   // zero k-pad cols 120..127
    *(int4*)&Zs[(wv * 16 + lane) * KP2 + 120] = make_int4(0, 0, 0, 0);
  __syncthreads();

  // ---- GEMM2: wave wv -> s-tiles [wv*6, wv*6+6), t-tiles 0..3 ----
  f32x4 acc2[4][6];
#pragma unroll
  for (int a = 0; a < 4; ++a)
#pragma unroll
    for (int b = 0; b < 6; ++b) acc2[a][b] = (f32x4)(0.f);
#pragma unroll
  for (int ks = 0; ks < 4; ++ks) {
    bf16x8 av[4];
#pragma unroll
    for (int tf = 0; tf < 4; ++tf)
      av[tf] = *(const bf16x8*)&Zs[(tf * 16 + col) * KP2 + ks * 32 + kq];
#pragma unroll
    for (int st = 0; st < 6; ++st) {
      bf16x8 b = *(const bf16x8*)(W2 + ((wv * 6 + st) * 16 + col) * 128 + ks * 32 + kq);
#pragma unroll
      for (int tf = 0; tf < 4; ++tf)
        acc2[tf][st] = __builtin_amdgcn_mfma_f32_16x16x32_bf16(av[tf], b, acc2[tf][st], 0, 0, 0);
    }
  }

  // ---- stage skip part into SG (Xs reuse; all Xs reads done at sync2) ----
  short* SG = Xs;
#pragma unroll
  for (int st = 0; st < 6; ++st) {
    const int tile = wv * 6 + st;
    if (tile < 15) {
      const int s = tile * 16 + col;
      const float b2 = bias2[s];
#pragma unroll
      for (int tf = 0; tf < 4; ++tf)
#pragma unroll
        for (int reg = 0; reg < 4; ++reg)
          SG[(tf * 16 + quad * 4 + reg) * SGP + s] = f2bf(acc2[tf][st][reg] + b2);
    }
  }
  __syncthreads();

  // ---- cooperative vectorized skips RMW: 64 rows x 240 shorts ----
  {
    const size_t srow = ((size_t)bb * L_ + t0) * 240;
#pragma unroll
    for (int it = 0; it < 8; ++it) {
      const int idx = tid + it * 256;
      if (idx < 1920) {
        const int row = idx / 30;
        const int j = idx - row * 30;
        unsigned short* gp = skips + srow + row * 240 + j * 8;
        int4 sv = *(const int4*)&SG[row * SGP + j * 8];
        const unsigned short* svp = (const unsigned short*)&sv;
        float vals[8];
#pragma unroll
        for (int e = 0; e < 8; ++e) vals[e] = bf2f(svp[e]);
        if (!first) {
          int4 ov = *(const int4*)gp;
          const unsigned short* ovp = (const unsigned short*)&ov;
#pragma unroll
          for (int e = 0; e < 8; ++e) vals[e] += bf2f(ovp[e]);
        }
        int4 res;
        unsigned short* rp = (unsigned short*)&res;
#pragma unroll
        for (int e = 0; e < 8; ++e) rp[e] = (unsigned short)f2bf(vals[e]);
        *(int4*)gp = res;
      }
    }
  }

  // ---- res epilogue (scalar f32, 64B-coalesced across cols) ----
#pragma unroll
  for (int st = 0; st < 6; ++st) {
    const int tile = wv * 6 + st;
    if (tile >= 15 && tile < 23) {
      const int s = tile * 16 + col;
      const int r = s - 240;
      if (r < 120) {
        const float b2 = bias2[s];
#pragma unroll
        for (int tf = 0; tf < 4; ++tf) {
#pragma unroll
          for (int reg = 0; reg < 4; ++reg) {
            const int t = tf * 16 + quad * 4 + reg;
            const size_t gi = ((size_t)(bb * L_ + t0 + t)) * 128 + r;
            res_out[gi] = res_in[gi] + acc2[tf][st][reg] + b2;
          }
        }
      }
    }
  }
}

// ---------------------------------------------------------------------------
// Head with 4-way q-split per wave (B reuse x4). Separate Hs buffer.
// ---------------------------------------------------------------------------
#define KPH 264

__global__ __launch_bounds__(256, 2) void head_mfma_kernel(
    const unsigned short* __restrict__ skips,
    const short* __restrict__ Wh1, const short* __restrict__ Wh2,
    const float* __restrict__ bh1, const float* __restrict__ bh2,
    float* __restrict__ out)
{
  __shared__ __align__(16) short Ss[64 * KPH];
  __shared__ __align__(16) short Hs[64 * KPH];

  const int tid = threadIdx.x;
  const int bb = blockIdx.y;
  const int t0 = blockIdx.x * 64;

  for (int idx = tid; idx < 2048; idx += 256) {
    const int c = idx & 31, trw = idx >> 5;
    if (c < 30) {
      int4 v = *(const int4*)(skips + ((size_t)(bb * L_ + t0 + trw) * 240 + c * 8));
      int* vi = (int*)&v;
#pragma unroll
      for (int j = 0; j < 4; ++j) {
        unsigned x = (unsigned)vi[j];
        unsigned lo = x & 0xFFFFu; if (lo & 0x8000u) lo = 0;
        unsigned hi = x >> 16;     if (hi & 0x8000u) hi = 0;
        vi[j] = (int)(lo | (hi << 16));
      }
      *(int4*)&Ss[trw * KPH + c * 8] = v;
    } else {
      *(int4*)&Ss[trw * KPH + c * 8] = make_int4(0, 0, 0, 0);
    }
  }
  __syncthreads();

  const int lane = tid & 63;
  const int wv = tid >> 6;
  const int col = lane & 15;
  const int quad = lane >> 4;
  const int kq = quad * 8;

  f32x4 acc[4][4];
#pragma unroll
  for (int a = 0; a < 4; ++a)
#pragma unroll
    for (int b = 0; b < 4; ++b) acc[a][b] = (f32x4)(0.f);
#pragma unroll
  for (int ks = 0; ks < 8; ++ks) {
    bf16x8 av[4];
#pragma unroll
    for (int tf = 0; tf < 4; ++tf)
      av[tf] = *(const bf16x8*)&Ss[(tf * 16 + col) * KPH + ks * 32 + kq];
#pragma unroll
    for (int ct = 0; ct < 4; ++ct) {
      bf16x8 b = *(const bf16x8*)(Wh1 + ((wv * 4 + ct) * 16 + col) * 256 + ks * 32 + kq);
#pragma unroll
      for (int tf = 0; tf < 4; ++tf)
        acc[tf][ct] = __builtin_amdgcn_mfma_f32_16x16x32_bf16(av[tf], b, acc[tf][ct], 0, 0, 0);
    }
  }
#pragma unroll
  for (int ct = 0; ct < 4; ++ct) {
    const int q = (wv * 4 + ct) * 16 + col;
    const float b1 = bh1[q];
#pragma unroll
    for (int tf = 0; tf < 4; ++tf)
#pragma unroll
      for (int reg = 0; reg < 4; ++reg)
        Hs[(tf * 16 + quad * 4 + reg) * KPH + q] = f2bf(fmaxf(acc[tf][ct][reg] + b1, 0.0f));
  }
  __syncthreads();

  f32x4 acc2[4][4];
#pragma unroll
  for (int a = 0; a < 4; ++a)
#pragma unroll
    for (int b = 0; b < 4; ++b) acc2[a][b] = (f32x4)(0.f);
#pragma unroll
  for (int ks = 0; ks < 8; ++ks) {
    bf16x8 av[4];
#pragma unroll
    for (int tf = 0; tf < 4; ++tf)
      av[tf] = *(const bf16x8*)&Hs[(tf * 16 + col) * KPH + ks * 32 + kq];
#pragma unroll
    for (int ct = 0; ct < 4; ++ct) {
      bf16x8 b = *(const bf16x8*)(Wh2 + ((wv * 4 + ct) * 16 + col) * 256 + ks * 32 + kq);
#pragma unroll
      for (int tf = 0; tf < 4; ++tf)
        acc2[tf][ct] = __builtin_amdgcn_mfma_f32_16x16x32_bf16(av[tf], b, acc2[tf][ct], 0, 0, 0);
    }
  }
#pragma unroll
  for (int ct = 0; ct < 4; ++ct) {
    const int q = (wv * 4 + ct) * 16 + col;
    const float b2 = bh2[q];
#pragma unroll
    for (int tf = 0; tf < 4; ++tf) {
      const int tg0 = t0 + tf * 16 + quad * 4;
      float4 o = make_float4(acc2[tf][ct][0] + b2, acc2[tf][ct][1] + b2,
                             acc2[tf][ct][2] + b2, acc2[tf][ct][3] + b2);
      *(float4*)(out + ((size_t)(bb * Q_ + q)) * L_ + tg0) = o;
    }
  }
}

// ---------------------------------------------------------------------------
extern "C" void kernel_launch(void* const* d_in, const int* in_sizes, int n_in,
                              void* d_out, int out_size, void* d_ws, size_t ws_size,
                              hipStream_t stream) {
  const float* wav    = (const float*)d_in[0];
  const float* mel    = (const float*)d_in[1];
  const float* w_up   = (const float*)d_in[2];
  const float* b_up   = (const float*)d_in[3];
  const float* w_in   = (const float*)d_in[4];
  const float* b_in   = (const float*)d_in[5];
  const float* w_gate = (const float*)d_in[6];
  const float* b_gate = (const float*)d_in[7];
  const float* w_cond = (const float*)d_in[8];
  const float* b_cond = (const float*)d_in[9];
  const float* w_res  = (const float*)d_in[10];
  const float* b_res  = (const float*)d_in[11];
  const float* w_skip = (const float*)d_in[12];
  const float* b_skip = (const float*)d_in[13];
  const float* w_h1   = (const float*)d_in[14];
  const float* b_h1   = (const float*)d_in[15];
  const float* w_h2   = (const float*)d_in[16];
  const float* b_h2   = (const float*)d_in[17];
  float* out = (float*)d_out;

  char* w = (char*)d_ws;
  short* condb   = (short*)w;                 w += (size_t)B_ * L_ * M_ * 2;
  float* res0    = (float*)w;                 w += (size_t)B_ * L_ * 128 * 4;
  float* res1    = (float*)w;                 w += (size_t)B_ * L_ * 128 * 4;
  unsigned short* skips = (unsigned short*)w; w += (size_t)B_ * L_ * 240 * 2;
  short* W1p     = (short*)w;                 w += (size_t)16 * 256 * 320 * 2;
  short* W2p     = (short*)w;                 w += (size_t)16 * 384 * 128 * 2;
  short* Wh1p    = (short*)w;                 w += (size_t)256 * 256 * 2;
  short* Wh2p    = (short*)w;                 w += (size_t)256 * 256 * 2;
  float* bias1p  = (float*)w;                 w += (size_t)16 * 240 * 4;
  float* bias2p  = (float*)w;                 w += (size_t)16 * 384 * 4;
  short* melT    = (short*)w;                 w += (size_t)B_ * TMEL * M_ * 2;
  // Wup (13.1 MB) overlays skips: consumed before first block kernel (first=1
  // re-initializes skips without reading).
  short* Wup = (short*)skips;

  prepack_w1_kernel<<<(16 * 256 * 320) / 256, 256, 0, stream>>>(w_gate, w_cond, W1p);
  prepack_w2_kernel<<<(16 * 384 * 128) / 256, 256, 0, stream>>>(w_skip, w_res, W2p);
  prepack_rest_kernel<<<141056 / 256, 256, 0, stream>>>(
      w_h1, w_h2, b_gate, b_cond, b_skip, b_res, Wh1p, Wh2p, bias1p, bias2p);
  prep_melT_kernel<<<(B_ * TMEL * M_ + 255) / 256, 256, 0, stream>>>(mel, melT);
  prep_wup_kernel<<<80 * 4 * 4, 256, 0, stream>>>(w_up, Wup);

  dim3 ugrid(256, 4);
  upsample_mfma_kernel<<<ugrid, 256, 0, stream>>>(melT, Wup, b_up, condb);
  in_conv_kernel<<<((size_t)B_ * L_ * 128) / 256, 256, 0, stream>>>(wav, w_in, b_in, res0);

  dim3 bgrid(L_ / 64, B_);
  for (int i = 0; i < NB_; ++i) {
    const int d = 1 << (i & 7);
    const float* rin  = (i & 1) ? res1 : res0;
    float*       rout = (i & 1) ? res0 : res1;
    block_mfma_kernel<<<bgrid, 256, 0, stream>>>(
        rin, rout, skips, condb,
        W1p + (size_t)i * 256 * 320, W2p + (size_t)i * 384 * 128,
        bias1p + i * 240, bias2p + i * 384,
        d, (i == 0) ? 1 : 0);
  }

  head_mfma_kernel<<<bgrid, 256, 0, stream>>>(skips, Wh1p, Wh2p, b_h1, b_h2, out);
}

// Round 4
// 1108.604 us; speedup vs baseline: 7.2636x; 1.2970x over previous
//
#include <hip/hip_runtime.h>
#include <math.h>

#define B_   4
#define M_   80
#define TMEL 63
#define R_   120
#define S_   240
#define Q_   256
#define NB_  16
#define L_   15872

typedef float  f32x4  __attribute__((ext_vector_type(4)));
typedef short  bf16x8 __attribute__((ext_vector_type(8)));
typedef short  short4_t __attribute__((ext_vector_type(4)));

__device__ __forceinline__ short f2bf(float x) {
  unsigned u = __builtin_bit_cast(unsigned, x);
  u += 0x7fffu + ((u >> 16) & 1u);
  return (short)(u >> 16);
}
__device__ __forceinline__ float bf2f(unsigned short s) {
  unsigned u = ((unsigned)s) << 16;
  return __builtin_bit_cast(float, u);
}

// ---------------------------------------------------------------------------
// melT[b][i][m] bf16  <-  mel[b][m][i] f32
// ---------------------------------------------------------------------------
__global__ __launch_bounds__(256) void prep_melT_kernel(
    const float* __restrict__ mel, short* __restrict__ melT)
{
  const int idx = blockIdx.x * 256 + threadIdx.x;
  if (idx >= B_ * TMEL * M_) return;
  const int m = idx % M_;
  const int i = (idx / M_) % TMEL;
  const int b = idx / (M_ * TMEL);
  melT[idx] = f2bf(mel[b * (M_ * TMEL) + m * TMEL + i]);
}

// ---------------------------------------------------------------------------
// Wup[phi][c][j*80+m] bf16: tap j <-> delta = dmin(phi)+j, q = 400+phi+256*delta
// ---------------------------------------------------------------------------
__global__ __launch_bounds__(256) void prep_wup_kernel(
    const float* __restrict__ w_up, short* __restrict__ Wup)
{
  __shared__ float T[M_][65];
  const int c  = blockIdx.x >> 4;
  const int j  = (blockIdx.x >> 2) & 3;
  const int fb = blockIdx.x & 3;
  for (int idx = threadIdx.x; idx < M_ * 64; idx += 256) {
    const int pl = idx & 63, m = idx >> 6;
    const int phi = fb * 64 + pl;
    const int dmin = (phi < 112) ? -1 : -2;
    const int dmax = (phi < 144) ? 1 : 0;
    const int delta = dmin + j;
    float v = 0.0f;
    if (delta <= dmax)
      v = w_up[m * (M_ * 800) + c * 800 + (400 + phi + 256 * delta)];
    T[m][pl] = v;
  }
  __syncthreads();
  for (int idx = threadIdx.x; idx < 64 * M_; idx += 256) {
    const int m = idx % M_, pl = idx / M_;
    const int phi = fb * 64 + pl;
    Wup[((size_t)phi * M_ + c) * 320 + j * 80 + m] = f2bf(T[m][pl]);
  }
}

// ---------------------------------------------------------------------------
// Upsample as per-phase MFMA GEMM -> condb[b][t][80] bf16
// ---------------------------------------------------------------------------
#define KPU 328

__global__ __launch_bounds__(256, 2) void upsample_mfma_kernel(
    const short* __restrict__ melT, const short* __restrict__ Wup,
    const float* __restrict__ b_up, short* __restrict__ condb)
{
  __shared__ __align__(16) short Xu[64 * KPU];
  const int tid = threadIdx.x;
  const int phi = blockIdx.x;
  const int r0 = blockIdx.y * 64;
  const int dmin = (phi < 112) ? -1 : -2;

  for (int idx = tid; idx < 2560; idx += 256) {
    const int v = idx % 10;
    const int j = (idx / 10) & 3;
    const int rl = idx / 40;
    const int rho = r0 + rl;
    const int b = rho / 62;
    const int n = rho - b * 62;
    const int i = n - (dmin + j);
    int4 val = make_int4(0, 0, 0, 0);
    if (b < B_ && i >= 0 && i < TMEL)
      val = *(const int4*)&melT[((size_t)b * TMEL + i) * M_ + v * 8];
    *(int4*)&Xu[rl * KPU + j * 80 + v * 8] = val;
  }
  __syncthreads();

  const int lane = tid & 63;
  const int wv = tid >> 6;
  const int col = lane & 15;
  const int quad = lane >> 4;
  const int kq = quad * 8;

  f32x4 acc[5];
#pragma unroll
  for (int i = 0; i < 5; ++i) acc[i] = (f32x4)(0.f);
#pragma unroll
  for (int ks = 0; ks < 10; ++ks) {
    bf16x8 a = *(const bf16x8*)&Xu[(wv * 16 + col) * KPU + ks * 32 + kq];
#pragma unroll
    for (int ct = 0; ct < 5; ++ct) {
      bf16x8 b = *(const bf16x8*)(Wup + ((size_t)phi * M_ + ct * 16 + col) * 320 + ks * 32 + kq);
      acc[ct] = __builtin_amdgcn_mfma_f32_16x16x32_bf16(a, b, acc[ct], 0, 0, 0);
    }
  }
#pragma unroll
  for (int ct = 0; ct < 5; ++ct) {
    const int c = ct * 16 + col;
    const float bc = b_up[c];
#pragma unroll
    for (int reg = 0; reg < 4; ++reg) {
      const int rho = r0 + wv * 16 + quad * 4 + reg;
      if (rho < 248) {
        const int b = rho / 62;
        const int n = rho - b * 62;
        const int t = phi + (n << 8);
        condb[((size_t)b * L_ + t) * M_ + c] = f2bf(acc[ct][reg] + bc);
      }
    }
  }
}

// res0[b][t][128] fp32
__global__ __launch_bounds__(256) void in_conv_kernel(
    const float* __restrict__ wav, const float* __restrict__ w_in,
    const float* __restrict__ b_in, float* __restrict__ res)
{
  const int idx = blockIdx.x * 256 + threadIdx.x;
  const int r = idx & 127;
  const int rem = idx >> 7;
  const int t = rem % L_;
  const int b = rem / L_;
  res[idx] = (r < R_) ? (w_in[r] * wav[b * L_ + t] + b_in[r]) : 0.0f;
}

// ---------------------------------------------------------------------------
// Weight prepacks
// ---------------------------------------------------------------------------
__global__ __launch_bounds__(256) void prepack_w1_kernel(
    const float* __restrict__ wg, const float* __restrict__ wc,
    short* __restrict__ W1p)
{
  const int idx = blockIdx.x * 256 + threadIdx.x;   // 16*256*320
  const int k = idx % 320;
  const int cp = (idx / 320) % 256;
  const int i = idx / (320 * 256);
  float val = 0.0f;
  if (cp < 240) {
    const int r = cp >> 1;
    const int corig = (cp & 1) ? (120 + r) : r;
    if (k < 120)      val = wg[((size_t)(i * 240 + corig) * 120 + k) * 2 + 0];
    else if (k < 240) val = wg[((size_t)(i * 240 + corig) * 120 + (k - 120)) * 2 + 1];
    else              val = wc[(size_t)(i * 240 + corig) * 80 + (k - 240)];
  }
  W1p[idx] = f2bf(val);
}

__global__ __launch_bounds__(256) void prepack_w2_kernel(
    const float* __restrict__ wsk, const float* __restrict__ wr,
    short* __restrict__ W2p)
{
  const int idx = blockIdx.x * 256 + threadIdx.x;   // 16*384*128
  const int k = idx % 128;
  const int sp = (idx / 128) % 384;
  const int i = idx / (128 * 384);
  float val = 0.0f;
  if (k < 120) {
    if (sp < 240)      val = wsk[(size_t)(i * 240 + sp) * 120 + k];
    else if (sp < 360) val = wr[(size_t)(i * 120 + (sp - 240)) * 120 + k];
  }
  W2p[idx] = f2bf(val);
}

__global__ __launch_bounds__(256) void prepack_rest_kernel(
    const float* __restrict__ wh1, const float* __restrict__ wh2,
    const float* __restrict__ bg, const float* __restrict__ bc,
    const float* __restrict__ bs, const float* __restrict__ br,
    short* __restrict__ Wh1p, short* __restrict__ Wh2p,
    float* __restrict__ bias1p, float* __restrict__ bias2p)
{
  const int idx = blockIdx.x * 256 + threadIdx.x;   // 141056
  if (idx < 65536) {
    const int q = idx >> 8, k = idx & 255;
    Wh1p[idx] = f2bf(k < 240 ? wh1[q * 240 + k] : 0.0f);
  } else if (idx < 131072) {
    Wh2p[idx - 65536] = f2bf(wh2[idx - 65536]);
  } else if (idx < 134912) {
    const int j = idx - 131072;
    const int i = j / 240, cp = j % 240;
    const int r = cp >> 1;
    const int corig = (cp & 1) ? (120 + r) : r;
    bias1p[j] = bg[i * 240 + corig] + bc[i * 240 + corig];
  } else if (idx < 141056) {
    const int j = idx - 134912;
    const int i = j / 384, sp = j % 384;
    float v = 0.0f;
    if (sp < 240)      v = bs[i * 240 + sp];
    else if (sp < 360) v = br[i * 120 + (sp - 240)];
    bias2p[j] = v;
  }
}

// ---------------------------------------------------------------------------
// MFMA residual block. 512 threads / 8 waves, 2 WG/CU -> 16 waves/CU.
// Wave wv: GEMM1 c-tiles {2wv,2wv+1} x t-tiles 0..3 (4x B reuse);
//          GEMM2 s-tiles {3wv..3wv+2} x t-tiles 0..3.
// Merged-tap staging: for d<=64 load union of the two tap windows once.
// ---------------------------------------------------------------------------
#define KP1 328
#define KP2 136
#define SGP 248

__global__ __launch_bounds__(512, 4) void block_mfma_kernel(
    const float* __restrict__ res_in, float* __restrict__ res_out,
    unsigned short* __restrict__ skips, const short* __restrict__ condb,
    const short* __restrict__ W1, const short* __restrict__ W2,
    const float* __restrict__ bias1, const float* __restrict__ bias2,
    const int d, const int first)
{
  __shared__ __align__(16) short Xs[64 * KP1];
  __shared__ __align__(16) short Zs[64 * KP2];

  const int tid = threadIdx.x;
  const int bb = blockIdx.y;
  const int t0 = blockIdx.x * 64;

  // ---- stage X (merged taps): k [0,120)=res[t-d], [120,240)=res[t], [240,320)=cond
  {
    const int dd = (d <= 64) ? d : 64;
    const int nr = 64 + dd;               // rows to load
    for (int idx = tid; idx < nr * 30; idx += 512) {
      const int rr = idx / 30, c4 = idx - rr * 30;
      int ts;
      if (d <= 64)      ts = t0 - d + rr;
      else              ts = (rr < 64) ? (t0 - 128 + rr) : (t0 + rr - 64);
      float4 v = make_float4(0.f, 0.f, 0.f, 0.f);
      if (ts >= 0)
        v = *(const float4*)(res_in + ((size_t)(bb * L_ + ts) * 128 + c4 * 4));
      short4_t s;
      s.x = f2bf(v.x); s.y = f2bf(v.y); s.z = f2bf(v.z); s.w = f2bf(v.w);
      if (rr < 64)
        *(short4_t*)&Xs[rr * KP1 + c4 * 4] = s;                 // tap0
      const int r1 = rr - dd;
      if (r1 >= 0)
        *(short4_t*)&Xs[r1 * KP1 + 120 + c4 * 4] = s;           // tap1
    }
  }
  for (int idx = tid; idx < 640; idx += 512) {
    const int c = idx % 10, trw = idx / 10;
    const int4 v = *(const int4*)(condb + ((size_t)(bb * L_ + t0 + trw) * M_ + c * 8));
    *(int4*)&Xs[trw * KP1 + 240 + c * 8] = v;
  }
  __syncthreads();

  const int lane = tid & 63;
  const int wv = tid >> 6;
  const int col = lane & 15;
  const int quad = lane >> 4;
  const int kq = quad * 8;

  // ---- GEMM1 ----
  f32x4 acc[4][2];   // [tf][ct]
#pragma unroll
  for (int a = 0; a < 4; ++a)
#pragma unroll
    for (int b = 0; b < 2; ++b) acc[a][b] = (f32x4)(0.f);
#pragma unroll
  for (int ks = 0; ks < 10; ++ks) {
    bf16x8 av[4];
#pragma unroll
    for (int tf = 0; tf < 4; ++tf)
      av[tf] = *(const bf16x8*)&Xs[(tf * 16 + col) * KP1 + ks * 32 + kq];
#pragma unroll
    for (int ct = 0; ct < 2; ++ct) {
      bf16x8 b = *(const bf16x8*)(W1 + ((wv * 2 + ct) * 16 + col) * 320 + ks * 32 + kq);
#pragma unroll
      for (int tf = 0; tf < 4; ++tf)
        acc[tf][ct] = __builtin_amdgcn_mfma_f32_16x16x32_bf16(av[tf], b, acc[tf][ct], 0, 0, 0);
    }
  }

  // ---- gating: even col = f, odd col = g; z -> Zs[t][r] ----
#pragma unroll
  for (int ct = 0; ct < 2; ++ct) {
    const int tile = wv * 2 + ct;
    if (tile < 15) {
      const int cp = tile * 16 + col;
      const float bias = bias1[cp];
#pragma unroll
      for (int tf = 0; tf < 4; ++tf) {
#pragma unroll
        for (int reg = 0; reg < 4; ++reg) {
          float v = acc[tf][ct][reg] + bias;
          v = fminf(fmaxf(v, -15.f), 15.f);
          const float e = __expf((lane & 1) ? -v : 2.0f * v);
          const float rc = __builtin_amdgcn_rcpf(e + 1.0f);
          const float u = (lane & 1) ? rc : (e - 1.0f) * rc;
          const float p = __shfl_xor(u, 1, 64);
          if (!(lane & 1)) {
            const int t = tf * 16 + quad * 4 + reg;
            Zs[t * KP2 + tile * 8 + (col >> 1)] = f2bf(u * p);
          }
        }
      }
    }
  }
  if (tid < 64)   // zero k-pad cols 120..127
    *(int4*)&Zs[tid * KP2 + 120] = make_int4(0, 0, 0, 0);
  __syncthreads();

  // ---- GEMM2 ----
  f32x4 acc2[4][3];
#pragma unroll
  for (int a = 0; a < 4; ++a)
#pragma unroll
    for (int b = 0; b < 3; ++b) acc2[a][b] = (f32x4)(0.f);
#pragma unroll
  for (int ks = 0; ks < 4; ++ks) {
    bf16x8 av[4];
#pragma unroll
    for (int tf = 0; tf < 4; ++tf)
      av[tf] = *(const bf16x8*)&Zs[(tf * 16 + col) * KP2 + ks * 32 + kq];
#pragma unroll
    for (int st = 0; st < 3; ++st) {
      bf16x8 b = *(const bf16x8*)(W2 + ((wv * 3 + st) * 16 + col) * 128 + ks * 32 + kq);
#pragma unroll
      for (int tf = 0; tf < 4; ++tf)
        acc2[tf][st] = __builtin_amdgcn_mfma_f32_16x16x32_bf16(av[tf], b, acc2[tf][st], 0, 0, 0);
    }
  }

  // ---- epilogue: waves 0-4 stage skip tiles into SG (Xs reuse; all Xs
  //      reads finished before previous barrier); waves 5-7 store res
  //      directly (64B-coalesced scalar f32) in parallel.
  short* SG = Xs;
#pragma unroll
  for (int st = 0; st < 3; ++st) {
    const int tile = wv * 3 + st;
    if (tile < 15) {
      const int s = tile * 16 + col;
      const float b2 = bias2[s];
#pragma unroll
      for (int tf = 0; tf < 4; ++tf)
#pragma unroll
        for (int reg = 0; reg < 4; ++reg)
          SG[(tf * 16 + quad * 4 + reg) * SGP + s] = f2bf(acc2[tf][st][reg] + b2);
    } else if (tile < 23) {
      const int s = tile * 16 + col;
      const int r = s - 240;
      if (r < 120) {
        const float b2 = bias2[s];
#pragma unroll
        for (int tf = 0; tf < 4; ++tf) {
#pragma unroll
          for (int reg = 0; reg < 4; ++reg) {
            const int t = tf * 16 + quad * 4 + reg;
            const size_t gi = ((size_t)(bb * L_ + t0 + t)) * 128 + r;
            res_out[gi] = res_in[gi] + acc2[tf][st][reg] + b2;
          }
        }
      }
    }
  }
  __syncthreads();

  // ---- cooperative vectorized skips RMW: 64 rows x 240 shorts ----
  {
    const size_t srow = ((size_t)bb * L_ + t0) * 240;
#pragma unroll
    for (int it = 0; it < 4; ++it) {
      const int idx = tid + it * 512;
      if (idx < 1920) {
        const int row = idx / 30;
        const int j = idx - row * 30;
        unsigned short* gp = skips + srow + row * 240 + j * 8;
        int4 sv = *(const int4*)&SG[row * SGP + j * 8];
        const unsigned short* svp = (const unsigned short*)&sv;
        float vals[8];
#pragma unroll
        for (int e = 0; e < 8; ++e) vals[e] = bf2f(svp[e]);
        if (!first) {
          int4 ov = *(const int4*)gp;
          const unsigned short* ovp = (const unsigned short*)&ov;
#pragma unroll
          for (int e = 0; e < 8; ++e) vals[e] += bf2f(ovp[e]);
        }
        int4 res;
        unsigned short* rp = (unsigned short*)&res;
#pragma unroll
        for (int e = 0; e < 8; ++e) rp[e] = (unsigned short)f2bf(vals[e]);
        *(int4*)gp = res;
      }
    }
  }
}

// ---------------------------------------------------------------------------
// Head with 4-way q-split per wave.
// ---------------------------------------------------------------------------
#define KPH 264

__global__ __launch_bounds__(256, 2) void head_mfma_kernel(
    const unsigned short* __restrict__ skips,
    const short* __restrict__ Wh1, const short* __restrict__ Wh2,
    const float* __restrict__ bh1, const float* __restrict__ bh2,
    float* __restrict__ out)
{
  __shared__ __align__(16) short Ss[64 * KPH];
  __shared__ __align__(16) short Hs[64 * KPH];

  const int tid = threadIdx.x;
  const int bb = blockIdx.y;
  const int t0 = blockIdx.x * 64;

  for (int idx = tid; idx < 2048; idx += 256) {
    const int c = idx & 31, trw = idx >> 5;
    if (c < 30) {
      int4 v = *(const int4*)(skips + ((size_t)(bb * L_ + t0 + trw) * 240 + c * 8));
      int* vi = (int*)&v;
#pragma unroll
      for (int j = 0; j < 4; ++j) {
        unsigned x = (unsigned)vi[j];
        unsigned lo = x & 0xFFFFu; if (lo & 0x8000u) lo = 0;
        unsigned hi = x >> 16;     if (hi & 0x8000u) hi = 0;
        vi[j] = (int)(lo | (hi << 16));
      }
      *(int4*)&Ss[trw * KPH + c * 8] = v;
    } else {
      *(int4*)&Ss[trw * KPH + c * 8] = make_int4(0, 0, 0, 0);
    }
  }
  __syncthreads();

  const int lane = tid & 63;
  const int wv = tid >> 6;
  const int col = lane & 15;
  const int quad = lane >> 4;
  const int kq = quad * 8;

  f32x4 acc[4][4];
#pragma unroll
  for (int a = 0; a < 4; ++a)
#pragma unroll
    for (int b = 0; b < 4; ++b) acc[a][b] = (f32x4)(0.f);
#pragma unroll
  for (int ks = 0; ks < 8; ++ks) {
    bf16x8 av[4];
#pragma unroll
    for (int tf = 0; tf < 4; ++tf)
      av[tf] = *(const bf16x8*)&Ss[(tf * 16 + col) * KPH + ks * 32 + kq];
#pragma unroll
    for (int ct = 0; ct < 4; ++ct) {
      bf16x8 b = *(const bf16x8*)(Wh1 + ((wv * 4 + ct) * 16 + col) * 256 + ks * 32 + kq);
#pragma unroll
      for (int tf = 0; tf < 4; ++tf)
        acc[tf][ct] = __builtin_amdgcn_mfma_f32_16x16x32_bf16(av[tf], b, acc[tf][ct], 0, 0, 0);
    }
  }
#pragma unroll
  for (int ct = 0; ct < 4; ++ct) {
    const int q = (wv * 4 + ct) * 16 + col;
    const float b1 = bh1[q];
#pragma unroll
    for (int tf = 0; tf < 4; ++tf)
#pragma unroll
      for (int reg = 0; reg < 4; ++reg)
        Hs[(tf * 16 + quad * 4 + reg) * KPH + q] = f2bf(fmaxf(acc[tf][ct][reg] + b1, 0.0f));
  }
  __syncthreads();

  f32x4 acc2[4][4];
#pragma unroll
  for (int a = 0; a < 4; ++a)
#pragma unroll
    for (int b = 0; b < 4; ++b) acc2[a][b] = (f32x4)(0.f);
#pragma unroll
  for (int ks = 0; ks < 8; ++ks) {
    bf16x8 av[4];
#pragma unroll
    for (int tf = 0; tf < 4; ++tf)
      av[tf] = *(const bf16x8*)&Hs[(tf * 16 + col) * KPH + ks * 32 + kq];
#pragma unroll
    for (int ct = 0; ct < 4; ++ct) {
      bf16x8 b = *(const bf16x8*)(Wh2 + ((wv * 4 + ct) * 16 + col) * 256 + ks * 32 + kq);
#pragma unroll
      for (int tf = 0; tf < 4; ++tf)
        acc2[tf][ct] = __builtin_amdgcn_mfma_f32_16x16x32_bf16(av[tf], b, acc2[tf][ct], 0, 0, 0);
    }
  }
#pragma unroll
  for (int ct = 0; ct < 4; ++ct) {
    const int q = (wv * 4 + ct) * 16 + col;
    const float b2 = bh2[q];
#pragma unroll
    for (int tf = 0; tf < 4; ++tf) {
      const int tg0 = t0 + tf * 16 + quad * 4;
      float4 o = make_float4(acc2[tf][ct][0] + b2, acc2[tf][ct][1] + b2,
                             acc2[tf][ct][2] + b2, acc2[tf][ct][3] + b2);
      *(float4*)(out + ((size_t)(bb * Q_ + q)) * L_ + tg0) = o;
    }
  }
}

// ---------------------------------------------------------------------------
extern "C" void kernel_launch(void* const* d_in, const int* in_sizes, int n_in,
                              void* d_out, int out_size, void* d_ws, size_t ws_size,
                              hipStream_t stream) {
  const float* wav    = (const float*)d_in[0];
  const float* mel    = (const float*)d_in[1];
  const float* w_up   = (const float*)d_in[2];
  const float* b_up   = (const float*)d_in[3];
  const float* w_in   = (const float*)d_in[4];
  const float* b_in   = (const float*)d_in[5];
  const float* w_gate = (const float*)d_in[6];
  const float* b_gate = (const float*)d_in[7];
  const float* w_cond = (const float*)d_in[8];
  const float* b_cond = (const float*)d_in[9];
  const float* w_res  = (const float*)d_in[10];
  const float* b_res  = (const float*)d_in[11];
  const float* w_skip = (const float*)d_in[12];
  const float* b_skip = (const float*)d_in[13];
  const float* w_h1   = (const float*)d_in[14];
  const float* b_h1   = (const float*)d_in[15];
  const float* w_h2   = (const float*)d_in[16];
  const float* b_h2   = (const float*)d_in[17];
  float* out = (float*)d_out;

  char* w = (char*)d_ws;
  short* condb   = (short*)w;                 w += (size_t)B_ * L_ * M_ * 2;
  float* res0    = (float*)w;                 w += (size_t)B_ * L_ * 128 * 4;
  float* res1    = (float*)w;                 w += (size_t)B_ * L_ * 128 * 4;
  unsigned short* skips = (unsigned short*)w; w += (size_t)B_ * L_ * 240 * 2;
  short* W1p     = (short*)w;                 w += (size_t)16 * 256 * 320 * 2;
  short* W2p     = (short*)w;                 w += (size_t)16 * 384 * 128 * 2;
  short* Wh1p    = (short*)w;                 w += (size_t)256 * 256 * 2;
  short* Wh2p    = (short*)w;                 w += (size_t)256 * 256 * 2;
  float* bias1p  = (float*)w;                 w += (size_t)16 * 240 * 4;
  float* bias2p  = (float*)w;                 w += (size_t)16 * 384 * 4;
  short* melT    = (short*)w;                 w += (size_t)B_ * TMEL * M_ * 2;
  // Wup (13.1 MB) overlays skips: consumed before first block kernel.
  short* Wup = (short*)skips;

  prepack_w1_kernel<<<(16 * 256 * 320) / 256, 256, 0, stream>>>(w_gate, w_cond, W1p);
  prepack_w2_kernel<<<(16 * 384 * 128) / 256, 256, 0, stream>>>(w_skip, w_res, W2p);
  prepack_rest_kernel<<<141056 / 256, 256, 0, stream>>>(
      w_h1, w_h2, b_gate, b_cond, b_skip, b_res, Wh1p, Wh2p, bias1p, bias2p);
  prep_melT_kernel<<<(B_ * TMEL * M_ + 255) / 256, 256, 0, stream>>>(mel, melT);
  prep_wup_kernel<<<80 * 4 * 4, 256, 0, stream>>>(w_up, Wup);

  dim3 ugrid(256, 4);
  upsample_mfma_kernel<<<ugrid, 256, 0, stream>>>(melT, Wup, b_up, condb);
  in_conv_kernel<<<((size_t)B_ * L_ * 128) / 256, 256, 0, stream>>>(wav, w_in, b_in, res0);

  dim3 bgrid(L_ / 64, B_);
  for (int i = 0; i < NB_; ++i) {
    const int d = 1 << (i & 7);
    const float* rin  = (i & 1) ? res1 : res0;
    float*       rout = (i & 1) ? res0 : res1;
    block_mfma_kernel<<<bgrid, 512, 0, stream>>>(
        rin, rout, skips, condb,
        W1p + (size_t)i * 256 * 320, W2p + (size_t)i * 384 * 128,
        bias1p + i * 240, bias2p + i * 384,
        d, (i == 0) ? 1 : 0);
  }

  head_mfma_kernel<<<bgrid, 256, 0, stream>>>(skips, Wh1p, Wh2p, b_h1, b_h2, out);
}